// Round 1
// 213.396 us; speedup vs baseline: 1.0435x; 1.0435x over previous
//
#include <hip/hip_runtime.h>

#define MWIN 2048
#define HH 8

typedef _Float16 half8 __attribute__((ext_vector_type(8)));
typedef _Float16 half4 __attribute__((ext_vector_type(4)));
typedef float f32x4 __attribute__((ext_vector_type(4)));

// ---------------- fp32 -> fp16 conversion (8 elements/thread) ----------------
__global__ __launch_bounds__(256) void k_cvt(const float* __restrict__ src,
                                             _Float16* __restrict__ dst, int n8) {
    int i = blockIdx.x * 256 + threadIdx.x;
    if (i >= n8) return;
    float4 a = ((const float4*)src)[i * 2];
    float4 b = ((const float4*)src)[i * 2 + 1];
    half8 h;
    h[0] = (_Float16)a.x; h[1] = (_Float16)a.y; h[2] = (_Float16)a.z; h[3] = (_Float16)a.w;
    h[4] = (_Float16)b.x; h[5] = (_Float16)b.y; h[6] = (_Float16)b.z; h[7] = (_Float16)b.w;
    ((half8*)dst)[i] = h;
}

// ---- MFMA GEMM, K=128. Column groups split across blockIdx.y (CGS cgs per block)
// to raise occupancy (was: 1 block per 256 rows doing ALL cgs serially -> 1.2
// blocks/CU, latency-bound at MfmaUtil 6.7%). A-tile re-reads hit LLC.
// IN_T=float fuses the fp32->fp16 convert into the fragment load (drops k_cvt(x)).
template <typename IN_T, typename OUT_T, int CGS>
__global__ __launch_bounds__(256) void k_mfma_gemm(const IN_T* __restrict__ A,
                                                   const _Float16* __restrict__ Bw,
                                                   const float* __restrict__ bias,
                                                   OUT_T* __restrict__ out, int ldo,
                                                   int N) {
    int tid = threadIdx.x;
    int lane = tid & 63, wv = tid >> 6;
    int m = lane & 15, q = lane >> 4;
    int row0 = blockIdx.x * 256 + wv * 64;

    // A fragments: 4 row-tiles x 4 k-steps, held for the whole kernel
    half8 a[4][4];
    #pragma unroll
    for (int rt = 0; rt < 4; ++rt) {
        int r = row0 + rt * 16 + m;
        r = r < N ? r : N - 1;
        const IN_T* ap = A + (size_t)r * 128 + q * 8;
        #pragma unroll
        for (int ks = 0; ks < 4; ++ks) {
            if constexpr (sizeof(IN_T) == 2) {
                a[rt][ks] = *(const half8*)(ap + ks * 32);
            } else {
                float4 f0 = *(const float4*)(ap + ks * 32);
                float4 f1 = *(const float4*)(ap + ks * 32 + 4);
                half8 h;
                h[0] = (_Float16)f0.x; h[1] = (_Float16)f0.y;
                h[2] = (_Float16)f0.z; h[3] = (_Float16)f0.w;
                h[4] = (_Float16)f1.x; h[5] = (_Float16)f1.y;
                h[6] = (_Float16)f1.z; h[7] = (_Float16)f1.w;
                a[rt][ks] = h;
            }
        }
    }

    #pragma unroll
    for (int cgi = 0; cgi < CGS; ++cgi) {
        int col0 = (blockIdx.y * CGS + cgi) * 64;
        f32x4 acc[4][4];
        #pragma unroll
        for (int ct = 0; ct < 4; ++ct) {
            float bv = bias ? bias[col0 + ct * 16 + m] : 0.f;
            #pragma unroll
            for (int rt = 0; rt < 4; ++rt) acc[rt][ct] = (f32x4){bv, bv, bv, bv};
        }
        #pragma unroll
        for (int ks = 0; ks < 4; ++ks) {
            half8 b[4];
            #pragma unroll
            for (int ct = 0; ct < 4; ++ct)
                b[ct] = *(const half8*)(Bw + (size_t)(col0 + ct * 16 + m) * 128 + q * 8 + ks * 32);
            #pragma unroll
            for (int rt = 0; rt < 4; ++rt)
                #pragma unroll
                for (int ct = 0; ct < 4; ++ct)
                    acc[rt][ct] = __builtin_amdgcn_mfma_f32_16x16x32_f16(a[rt][ks], b[ct], acc[rt][ct], 0, 0, 0);
        }
        #pragma unroll
        for (int rt = 0; rt < 4; ++rt) {
            #pragma unroll
            for (int reg = 0; reg < 4; ++reg) {
                int row = row0 + rt * 16 + q * 4 + reg;
                if (row >= N) continue;
                #pragma unroll
                for (int ct = 0; ct < 4; ++ct)
                    out[(size_t)row * ldo + col0 + ct * 16 + m] = (OUT_T)acc[rt][ct][reg];
            }
        }
    }
}

// ---- per-(window,head) kv & s reduction; wave per (w, 2h), no LDS/barriers ----
__global__ __launch_bounds__(256) void k_kv_accum(const _Float16* __restrict__ qkv,
                                                  const int* __restrict__ offsets,
                                                  const int* __restrict__ counts,
                                                  float* __restrict__ kv_t,
                                                  float* __restrict__ s) {
    int w = blockIdx.x;
    int wv = threadIdx.x >> 6, lane = threadIdx.x & 63;
    int d = lane & 15, eq = lane >> 4;
    int off = offsets[w], cnt = counts[w];
    #pragma unroll
    for (int hh = 0; hh < 2; ++hh) {
        int h = wv * 2 + hh;
        float acc0 = 0.f, acc1 = 0.f, acc2 = 0.f, acc3 = 0.f, sacc = 0.f;
        const _Float16* base = qkv + (size_t)off * 384 + h * 16;
        for (int p = 0; p < cnt; ++p) {
            const _Float16* row = base + (size_t)p * 384;
            float kk = (float)row[128 + d];
            kk = kk > 0.f ? kk : 0.f;
            half4 v4 = *(const half4*)(row + 256 + eq * 4);
            acc0 += kk * (float)v4[0];
            acc1 += kk * (float)v4[1];
            acc2 += kk * (float)v4[2];
            acc3 += kk * (float)v4[3];
            sacc += kk;
        }
        float* o = kv_t + (((size_t)(w * HH + h)) << 8);
        o[(eq * 4 + 0) * 16 + d] = acc0;
        o[(eq * 4 + 1) * 16 + d] = acc1;
        o[(eq * 4 + 2) * 16 + d] = acc2;
        o[(eq * 4 + 3) * 16 + d] = acc3;
        if (eq == 0) s[(((size_t)(w * HH + h)) << 4) + d] = sacc;
    }
}

// ------- fused 3x3 pool: fp32 in -> fp16 out, float4-granular -------
#define KV4 (MWIN * 512)
#define S4  (MWIN * 32)
__global__ __launch_bounds__(256) void k_pool_all(const float* __restrict__ kv_in,
                                                  _Float16* __restrict__ kv_out,
                                                  const float* __restrict__ s_in,
                                                  _Float16* __restrict__ s_out) {
    int idx = blockIdx.x * 256 + threadIdx.x;
    const float* in;
    _Float16* outp;
    int w, rest, shift;
    if (idx < KV4) {
        w = idx >> 9; rest = idx & 511; shift = 9;
        in = kv_in; outp = kv_out;
    } else {
        int j = idx - KV4;
        if (j >= S4) return;
        w = j >> 5; rest = j & 31; shift = 5;
        in = s_in; outp = s_out;
        idx = j;
    }
    int b = w >> 10, y = (w >> 5) & 31, xx = w & 31;
    f32x4 acc = {0.f, 0.f, 0.f, 0.f};
    #pragma unroll
    for (int dy = -1; dy <= 1; ++dy)
        #pragma unroll
        for (int dx = -1; dx <= 1; ++dx) {
            int ny = y + dy, nx = xx + dx;
            if (ny < 0 || ny >= 32 || nx < 0 || nx >= 32) continue;
            int nw = (b << 10) | (ny << 5) | nx;
            f32x4 v = ((const f32x4*)in)[((size_t)nw << shift) + rest];
            acc += v;
        }
    half4 hv;
    hv[0] = (_Float16)acc[0]; hv[1] = (_Float16)acc[1];
    hv[2] = (_Float16)acc[2]; hv[3] = (_Float16)acc[3];
    ((half4*)outp)[idx] = hv;
}

// ---------------- linear attention: one wave per (window, head), MFMA-based ----
// Was: one wave per window looping all 8 heads serially (512 blocks = 2
// blocks/CU, latency-bound). Nothing is reused across heads, so split h
// across waves: 4096 blocks.
__global__ __launch_bounds__(256) void k_attn(const _Float16* __restrict__ qkv,
                                              const _Float16* __restrict__ kvp,
                                              const _Float16* __restrict__ sp,
                                              const int* __restrict__ offsets,
                                              const int* __restrict__ counts,
                                              _Float16* __restrict__ y_h) {
    int gid = blockIdx.x * 4 + (threadIdx.x >> 6);
    int w = gid >> 3, h = gid & 7;
    int lane = threadIdx.x & 63;
    int col = lane & 15;
    int kq = lane >> 4;
    int off = offsets[w], cnt = counts[w];
    bool klive = kq < 2;
    int koff = (kq & 1) * 8;
    half8 zf = {};
    half8 t = *(const half8*)(kvp + ((((size_t)(w * HH + h)) << 8) + col * 16 + koff));
    half8 a_kv = klive ? t : zf;
    half8 t2 = *(const half8*)(sp + ((((size_t)(w * HH + h)) << 4) + koff));
    half8 a_s = klive ? t2 : zf;
    #pragma unroll
    for (int c = 0; c < 3; ++c) {
        int p = c * 16 + col;
        int pc = p < cnt ? p : cnt - 1;
        half8 qv = *(const half8*)(qkv + (size_t)(off + pc) * 384 + h * 16 + koff);
        #pragma unroll
        for (int i = 0; i < 8; ++i) qv[i] = qv[i] > (_Float16)0 ? qv[i] : (_Float16)0;
        half8 b_q = klive ? qv : zf;
        f32x4 acc = {};
        acc = __builtin_amdgcn_mfma_f32_16x16x32_f16(a_kv, b_q, acc, 0, 0, 0);
        f32x4 accs = {};
        accs = __builtin_amdgcn_mfma_f32_16x16x32_f16(a_s, b_q, accs, 0, 0, 0);
        float zinv = 1.f / (accs[0] + 1e-6f);
        half4 yo;
        #pragma unroll
        for (int i = 0; i < 4; ++i) yo[i] = (_Float16)(acc[i] * zinv);
        if (p < cnt)
            *(half4*)(y_h + (size_t)(off + p) * 128 + h * 16 + kq * 4) = yo;
    }
}

extern "C" void kernel_launch(void* const* d_in, const int* in_sizes, int n_in,
                              void* d_out, int out_size, void* d_ws, size_t ws_size,
                              hipStream_t stream) {
    const float* x     = (const float*)d_in[0];
    const float* Wqkv  = (const float*)d_in[1];
    const float* Wproj = (const float*)d_in[2];
    const float* bproj = (const float*)d_in[3];
    const int*   offsets = (const int*)d_in[4];
    const int*   counts  = (const int*)d_in[5];

    int N = in_sizes[0] / 128;

    char* ws = (char*)d_ws;
    float* kv_t = (float*)ws;                                    ws += (size_t)MWIN * HH * 256 * 4;
    float* s    = (float*)ws;                                    ws += (size_t)MWIN * HH * 16 * 4;
    _Float16* kvpt = (_Float16*)ws;                              ws += (size_t)MWIN * HH * 256 * 2;
    _Float16* sp   = (_Float16*)ws;                              ws += (size_t)MWIN * HH * 16 * 2;
    _Float16* qkv_h  = (_Float16*)ws;                            ws += (size_t)N * 384 * 2;
    _Float16* y_h    = (_Float16*)ws;                            ws += (size_t)N * 128 * 2;
    _Float16* Wqkv_h = (_Float16*)ws;                            ws += (size_t)384 * 128 * 2;
    _Float16* Wp_h   = (_Float16*)ws;                            ws += (size_t)128 * 128 * 2;
    float* out  = (float*)d_out;

    k_cvt<<<(384 * 128 / 8 + 255) / 256, 256, 0, stream>>>(Wqkv, Wqkv_h, 384 * 128 / 8);
    k_cvt<<<(128 * 128 / 8 + 255) / 256, 256, 0, stream>>>(Wproj, Wp_h, 128 * 128 / 8);

    int nrb = (N + 255) / 256;
    // QKV GEMM: fp32 A fused-converted, 2 col-groups/block, grid.y = 3
    k_mfma_gemm<float, _Float16, 2><<<dim3(nrb, 3), 256, 0, stream>>>(
        x, Wqkv_h, nullptr, qkv_h, 384, N);

    k_kv_accum<<<MWIN, 256, 0, stream>>>(qkv_h, offsets, counts, kv_t, s);

    k_pool_all<<<(KV4 + S4 + 255) / 256, 256, 0, stream>>>(kv_t, kvpt, s, sp);

    k_attn<<<MWIN * 2, 256, 0, stream>>>(qkv_h, kvpt, sp, offsets, counts, y_h);

    // Proj GEMM: 1 col-group/block, grid.y = 2
    k_mfma_gemm<_Float16, float, 1><<<dim3(nrb, 2), 256, 0, stream>>>(
        y_h, Wp_h, bproj, out, 128, N);
}

// Round 2
// 208.147 us; speedup vs baseline: 1.0699x; 1.0252x over previous
//
#include <hip/hip_runtime.h>

#define MWIN 2048
#define HH 8

typedef _Float16 half8 __attribute__((ext_vector_type(8)));
typedef _Float16 half4 __attribute__((ext_vector_type(4)));
typedef float f32x4 __attribute__((ext_vector_type(4)));

// ---------------- fp32 -> fp16 conversion (8 elements/thread) ----------------
__global__ __launch_bounds__(256) void k_cvt(const float* __restrict__ src,
                                             _Float16* __restrict__ dst, int n8) {
    int i = blockIdx.x * 256 + threadIdx.x;
    if (i >= n8) return;
    float4 a = ((const float4*)src)[i * 2];
    float4 b = ((const float4*)src)[i * 2 + 1];
    half8 h;
    h[0] = (_Float16)a.x; h[1] = (_Float16)a.y; h[2] = (_Float16)a.z; h[3] = (_Float16)a.w;
    h[4] = (_Float16)b.x; h[5] = (_Float16)b.y; h[6] = (_Float16)b.z; h[7] = (_Float16)b.w;
    ((half8*)dst)[i] = h;
}

// ---- MFMA GEMM, K=128. Column groups split across blockIdx.y.
// Epilogue: acc -> per-wave LDS tile (padded [32][68] f32, 2-way-free banks)
// -> wide dwordx4 global stores. Replaces 64 scalar 2B/4B stores per cg per
// wave (store-ack vmcnt-FIFO serialization, the round-0/1 ~40-50us invariant)
// with 8 (fp16) / 16 (fp32) 16B-per-lane coalesced stores.
template <typename IN_T, typename OUT_T, int CGS>
__global__ __launch_bounds__(256) void k_mfma_gemm(const IN_T* __restrict__ A,
                                                   const _Float16* __restrict__ Bw,
                                                   const float* __restrict__ bias,
                                                   OUT_T* __restrict__ out, int ldo,
                                                   int N) {
    __shared__ float st[4][32][68];   // 34.8 KB/block -> 4 blocks/CU LDS cap
    int tid = threadIdx.x;
    int lane = tid & 63, wv = tid >> 6;
    int m = lane & 15, q = lane >> 4;
    int row0 = blockIdx.x * 256 + wv * 64;
    float (*stw)[68] = st[wv];

    // A fragments: 4 row-tiles x 4 k-steps, held for the whole kernel
    half8 a[4][4];
    #pragma unroll
    for (int rt = 0; rt < 4; ++rt) {
        int r = row0 + rt * 16 + m;
        r = r < N ? r : N - 1;
        const IN_T* ap = A + (size_t)r * 128 + q * 8;
        #pragma unroll
        for (int ks = 0; ks < 4; ++ks) {
            if constexpr (sizeof(IN_T) == 2) {
                a[rt][ks] = *(const half8*)(ap + ks * 32);
            } else {
                float4 f0 = *(const float4*)(ap + ks * 32);
                float4 f1 = *(const float4*)(ap + ks * 32 + 4);
                half8 h;
                h[0] = (_Float16)f0.x; h[1] = (_Float16)f0.y;
                h[2] = (_Float16)f0.z; h[3] = (_Float16)f0.w;
                h[4] = (_Float16)f1.x; h[5] = (_Float16)f1.y;
                h[6] = (_Float16)f1.z; h[7] = (_Float16)f1.w;
                a[rt][ks] = h;
            }
        }
    }

    #pragma unroll
    for (int cgi = 0; cgi < CGS; ++cgi) {
        int col0 = (blockIdx.y * CGS + cgi) * 64;
        f32x4 acc[4][4];
        #pragma unroll
        for (int ct = 0; ct < 4; ++ct) {
            float bv = bias ? bias[col0 + ct * 16 + m] : 0.f;
            #pragma unroll
            for (int rt = 0; rt < 4; ++rt) acc[rt][ct] = (f32x4){bv, bv, bv, bv};
        }
        #pragma unroll
        for (int ks = 0; ks < 4; ++ks) {
            half8 b[4];
            #pragma unroll
            for (int ct = 0; ct < 4; ++ct)
                b[ct] = *(const half8*)(Bw + (size_t)(col0 + ct * 16 + m) * 128 + q * 8 + ks * 32);
            #pragma unroll
            for (int rt = 0; rt < 4; ++rt)
                #pragma unroll
                for (int ct = 0; ct < 4; ++ct)
                    acc[rt][ct] = __builtin_amdgcn_mfma_f32_16x16x32_f16(a[rt][ks], b[ct], acc[rt][ct], 0, 0, 0);
        }
        // ---- LDS-staged wide-store epilogue, two 32-row half-passes ----
        #pragma unroll
        for (int hp = 0; hp < 2; ++hp) {
            #pragma unroll
            for (int rh = 0; rh < 2; ++rh) {
                int rt = hp * 2 + rh;
                #pragma unroll
                for (int reg = 0; reg < 4; ++reg) {
                    int lr = rh * 16 + q * 4 + reg;
                    #pragma unroll
                    for (int ct = 0; ct < 4; ++ct)
                        stw[lr][ct * 16 + m] = acc[rt][ct][reg];
                }
            }
            if constexpr (sizeof(OUT_T) == 2) {
                #pragma unroll
                for (int ps = 0; ps < 4; ++ps) {
                    int r = ps * 8 + (lane >> 3), c0 = (lane & 7) * 8;
                    float4 f0 = *(const float4*)&stw[r][c0];
                    float4 f1 = *(const float4*)&stw[r][c0 + 4];
                    half8 h;
                    h[0] = (_Float16)f0.x; h[1] = (_Float16)f0.y;
                    h[2] = (_Float16)f0.z; h[3] = (_Float16)f0.w;
                    h[4] = (_Float16)f1.x; h[5] = (_Float16)f1.y;
                    h[6] = (_Float16)f1.z; h[7] = (_Float16)f1.w;
                    int grow = row0 + hp * 32 + r;
                    if (grow < N)
                        *(half8*)((_Float16*)out + (size_t)grow * ldo + col0 + c0) = h;
                }
            } else {
                #pragma unroll
                for (int ps = 0; ps < 8; ++ps) {
                    int r = ps * 4 + (lane >> 4), c0 = (lane & 15) * 4;
                    float4 f = *(const float4*)&stw[r][c0];
                    int grow = row0 + hp * 32 + r;
                    if (grow < N)
                        *(float4*)((float*)out + (size_t)grow * ldo + col0 + c0) = f;
                }
            }
        }
    }
}

// ---- per-(window,head) kv & s reduction; wave per (w, 2h), no LDS/barriers ----
// cnt is ~39-40; unroll x4 with grouped loads so 8 loads are in flight per
// batch instead of 2 dependent-latency loads per serial iteration.
__global__ __launch_bounds__(256) void k_kv_accum(const _Float16* __restrict__ qkv,
                                                  const int* __restrict__ offsets,
                                                  const int* __restrict__ counts,
                                                  float* __restrict__ kv_t,
                                                  float* __restrict__ s) {
    int w = blockIdx.x;
    int wv = threadIdx.x >> 6, lane = threadIdx.x & 63;
    int d = lane & 15, eq = lane >> 4;
    int off = offsets[w], cnt = counts[w];
    #pragma unroll
    for (int hh = 0; hh < 2; ++hh) {
        int h = wv * 2 + hh;
        float acc0 = 0.f, acc1 = 0.f, acc2 = 0.f, acc3 = 0.f, sacc = 0.f;
        const _Float16* base = qkv + (size_t)off * 384 + h * 16;
        int p = 0;
        for (; p + 4 <= cnt; p += 4) {
            _Float16 ka[4]; half4 va[4];
            #pragma unroll
            for (int u = 0; u < 4; ++u) {
                const _Float16* row = base + (size_t)(p + u) * 384;
                ka[u] = row[128 + d];
                va[u] = *(const half4*)(row + 256 + eq * 4);
            }
            #pragma unroll
            for (int u = 0; u < 4; ++u) {
                float kk = (float)ka[u];
                kk = kk > 0.f ? kk : 0.f;
                acc0 += kk * (float)va[u][0];
                acc1 += kk * (float)va[u][1];
                acc2 += kk * (float)va[u][2];
                acc3 += kk * (float)va[u][3];
                sacc += kk;
            }
        }
        for (; p < cnt; ++p) {
            const _Float16* row = base + (size_t)p * 384;
            float kk = (float)row[128 + d];
            kk = kk > 0.f ? kk : 0.f;
            half4 v4 = *(const half4*)(row + 256 + eq * 4);
            acc0 += kk * (float)v4[0];
            acc1 += kk * (float)v4[1];
            acc2 += kk * (float)v4[2];
            acc3 += kk * (float)v4[3];
            sacc += kk;
        }
        float* o = kv_t + (((size_t)(w * HH + h)) << 8);
        o[(eq * 4 + 0) * 16 + d] = acc0;
        o[(eq * 4 + 1) * 16 + d] = acc1;
        o[(eq * 4 + 2) * 16 + d] = acc2;
        o[(eq * 4 + 3) * 16 + d] = acc3;
        if (eq == 0) s[(((size_t)(w * HH + h)) << 4) + d] = sacc;
    }
}

// ------- fused 3x3 pool: fp32 in -> fp16 out, float4-granular -------
#define KV4 (MWIN * 512)
#define S4  (MWIN * 32)
__global__ __launch_bounds__(256) void k_pool_all(const float* __restrict__ kv_in,
                                                  _Float16* __restrict__ kv_out,
                                                  const float* __restrict__ s_in,
                                                  _Float16* __restrict__ s_out) {
    int idx = blockIdx.x * 256 + threadIdx.x;
    const float* in;
    _Float16* outp;
    int w, rest, shift;
    if (idx < KV4) {
        w = idx >> 9; rest = idx & 511; shift = 9;
        in = kv_in; outp = kv_out;
    } else {
        int j = idx - KV4;
        if (j >= S4) return;
        w = j >> 5; rest = j & 31; shift = 5;
        in = s_in; outp = s_out;
        idx = j;
    }
    int b = w >> 10, y = (w >> 5) & 31, xx = w & 31;
    f32x4 acc = {0.f, 0.f, 0.f, 0.f};
    #pragma unroll
    for (int dy = -1; dy <= 1; ++dy)
        #pragma unroll
        for (int dx = -1; dx <= 1; ++dx) {
            int ny = y + dy, nx = xx + dx;
            if (ny < 0 || ny >= 32 || nx < 0 || nx >= 32) continue;
            int nw = (b << 10) | (ny << 5) | nx;
            f32x4 v = ((const f32x4*)in)[((size_t)nw << shift) + rest];
            acc += v;
        }
    half4 hv;
    hv[0] = (_Float16)acc[0]; hv[1] = (_Float16)acc[1];
    hv[2] = (_Float16)acc[2]; hv[3] = (_Float16)acc[3];
    ((half4*)outp)[idx] = hv;
}

// ---------------- linear attention: one wave per (window, head), MFMA-based ----
__global__ __launch_bounds__(256) void k_attn(const _Float16* __restrict__ qkv,
                                              const _Float16* __restrict__ kvp,
                                              const _Float16* __restrict__ sp,
                                              const int* __restrict__ offsets,
                                              const int* __restrict__ counts,
                                              _Float16* __restrict__ y_h) {
    int gid = blockIdx.x * 4 + (threadIdx.x >> 6);
    int w = gid >> 3, h = gid & 7;
    int lane = threadIdx.x & 63;
    int col = lane & 15;
    int kq = lane >> 4;
    int off = offsets[w], cnt = counts[w];
    bool klive = kq < 2;
    int koff = (kq & 1) * 8;
    half8 zf = {};
    half8 t = *(const half8*)(kvp + ((((size_t)(w * HH + h)) << 8) + col * 16 + koff));
    half8 a_kv = klive ? t : zf;
    half8 t2 = *(const half8*)(sp + ((((size_t)(w * HH + h)) << 4) + koff));
    half8 a_s = klive ? t2 : zf;
    #pragma unroll
    for (int c = 0; c < 3; ++c) {
        int p = c * 16 + col;
        int pc = p < cnt ? p : cnt - 1;
        half8 qv = *(const half8*)(qkv + (size_t)(off + pc) * 384 + h * 16 + koff);
        #pragma unroll
        for (int i = 0; i < 8; ++i) qv[i] = qv[i] > (_Float16)0 ? qv[i] : (_Float16)0;
        half8 b_q = klive ? qv : zf;
        f32x4 acc = {};
        acc = __builtin_amdgcn_mfma_f32_16x16x32_f16(a_kv, b_q, acc, 0, 0, 0);
        f32x4 accs = {};
        accs = __builtin_amdgcn_mfma_f32_16x16x32_f16(a_s, b_q, accs, 0, 0, 0);
        float zinv = 1.f / (accs[0] + 1e-6f);
        half4 yo;
        #pragma unroll
        for (int i = 0; i < 4; ++i) yo[i] = (_Float16)(acc[i] * zinv);
        if (p < cnt)
            *(half4*)(y_h + (size_t)(off + p) * 128 + h * 16 + kq * 4) = yo;
    }
}

extern "C" void kernel_launch(void* const* d_in, const int* in_sizes, int n_in,
                              void* d_out, int out_size, void* d_ws, size_t ws_size,
                              hipStream_t stream) {
    const float* x     = (const float*)d_in[0];
    const float* Wqkv  = (const float*)d_in[1];
    const float* Wproj = (const float*)d_in[2];
    const float* bproj = (const float*)d_in[3];
    const int*   offsets = (const int*)d_in[4];
    const int*   counts  = (const int*)d_in[5];

    int N = in_sizes[0] / 128;

    char* ws = (char*)d_ws;
    float* kv_t = (float*)ws;                                    ws += (size_t)MWIN * HH * 256 * 4;
    float* s    = (float*)ws;                                    ws += (size_t)MWIN * HH * 16 * 4;
    _Float16* kvpt = (_Float16*)ws;                              ws += (size_t)MWIN * HH * 256 * 2;
    _Float16* sp   = (_Float16*)ws;                              ws += (size_t)MWIN * HH * 16 * 2;
    _Float16* x_h    = (_Float16*)ws;                            ws += (size_t)N * 128 * 2;
    _Float16* qkv_h  = (_Float16*)ws;                            ws += (size_t)N * 384 * 2;
    _Float16* y_h    = (_Float16*)ws;                            ws += (size_t)N * 128 * 2;
    _Float16* Wqkv_h = (_Float16*)ws;                            ws += (size_t)384 * 128 * 2;
    _Float16* Wp_h   = (_Float16*)ws;                            ws += (size_t)128 * 128 * 2;
    float* out  = (float*)d_out;

    int n8x = N * 128 / 8;
    k_cvt<<<(n8x + 255) / 256, 256, 0, stream>>>(x, x_h, n8x);
    k_cvt<<<(384 * 128 / 8 + 255) / 256, 256, 0, stream>>>(Wqkv, Wqkv_h, 384 * 128 / 8);
    k_cvt<<<(128 * 128 / 8 + 255) / 256, 256, 0, stream>>>(Wproj, Wp_h, 128 * 128 / 8);

    int nrb = (N + 255) / 256;
    // QKV GEMM: fp16 A (L3-resident after k_cvt), 2 col-groups/block, grid.y=3
    k_mfma_gemm<_Float16, _Float16, 2><<<dim3(nrb, 3), 256, 0, stream>>>(
        x_h, Wqkv_h, nullptr, qkv_h, 384, N);

    k_kv_accum<<<MWIN, 256, 0, stream>>>(qkv_h, offsets, counts, kv_t, s);

    k_pool_all<<<(KV4 + S4 + 255) / 256, 256, 0, stream>>>(kv_t, kvpt, s, sp);

    k_attn<<<MWIN * 2, 256, 0, stream>>>(qkv_h, kvpt, sp, offsets, counts, y_h);

    // Proj GEMM: 1 col-group/block, grid.y = 2
    k_mfma_gemm<_Float16, float, 1><<<dim3(nrb, 2), 256, 0, stream>>>(
        y_h, Wp_h, bproj, out, 128, N);
}

// Round 3
// 202.438 us; speedup vs baseline: 1.1000x; 1.0282x over previous
//
#include <hip/hip_runtime.h>

#define MWIN 2048
#define HH 8

typedef _Float16 half8 __attribute__((ext_vector_type(8)));
typedef _Float16 half4 __attribute__((ext_vector_type(4)));
typedef float f32x4 __attribute__((ext_vector_type(4)));

// ---------------- fp32 -> fp16 conversion (8 elements/thread) ----------------
__global__ __launch_bounds__(256) void k_cvt(const float* __restrict__ src,
                                             _Float16* __restrict__ dst, int n8) {
    int i = blockIdx.x * 256 + threadIdx.x;
    if (i >= n8) return;
    float4 a = ((const float4*)src)[i * 2];
    float4 b = ((const float4*)src)[i * 2 + 1];
    half8 h;
    h[0] = (_Float16)a.x; h[1] = (_Float16)a.y; h[2] = (_Float16)a.z; h[3] = (_Float16)a.w;
    h[4] = (_Float16)b.x; h[5] = (_Float16)b.y; h[6] = (_Float16)b.z; h[7] = (_Float16)b.w;
    ((half8*)dst)[i] = h;
}

// ---- weight fragmentizer: W fp32 [rows][128] -> MFMA-fragment-ordered fp16.
// Layout: frag[cg][ks][ct][lane] (half8 each). The GEMM b-load becomes ONE
// contiguous 1KB coalesced instruction instead of a 16-row x 256B-stride
// gather (16 cache lines/inst — the round-2 hidden cost in the hot loop).
__global__ __launch_bounds__(256) void k_prep_w(const float* __restrict__ Wqkv,
                                                const float* __restrict__ Wproj,
                                                _Float16* __restrict__ fq,
                                                _Float16* __restrict__ fp) {
    int tid = blockIdx.x * 256 + threadIdx.x;
    const float* src;
    _Float16* dst;
    if (tid < 6144) { src = Wqkv; dst = fq; }
    else {
        tid -= 6144;
        if (tid >= 2048) return;
        src = Wproj; dst = fp;
    }
    int lane = tid & 63, r = tid >> 6;
    int ct = r & 3, ks = (r >> 2) & 3, cg = r >> 4;
    int m = lane & 15, q = lane >> 4;
    const float* s_ = src + (size_t)(cg * 64 + ct * 16 + m) * 128 + q * 8 + ks * 32;
    float4 f0 = *(const float4*)s_;
    float4 f1 = *(const float4*)(s_ + 4);
    half8 h;
    h[0] = (_Float16)f0.x; h[1] = (_Float16)f0.y; h[2] = (_Float16)f0.z; h[3] = (_Float16)f0.w;
    h[4] = (_Float16)f1.x; h[5] = (_Float16)f1.y; h[6] = (_Float16)f1.z; h[7] = (_Float16)f1.w;
    *(half8*)(dst + (size_t)tid * 8) = h;
}

// ---- MFMA GEMM, K=128. B pre-fragmentized (coalesced 1KB loads, L1-broadcast
// across the block's 4 waves). Column groups split across blockIdx.y.
// Epilogue: acc -> per-wave padded LDS tile -> wide dwordx4 stores.
// RELU: applied to output columns < 256 (q,k of qkv) in the epilogue,
// removing the clamps from k_kv_accum / k_attn.
template <typename OUT_T, int CGS, bool RELU>
__global__ __launch_bounds__(256) void k_mfma_gemm(const _Float16* __restrict__ A,
                                                   const half8* __restrict__ Bfrag,
                                                   const float* __restrict__ bias,
                                                   OUT_T* __restrict__ out, int ldo,
                                                   int N) {
    __shared__ float st[4][32][68];
    int tid = threadIdx.x;
    int lane = tid & 63, wv = tid >> 6;
    int m = lane & 15, q = lane >> 4;
    int row0 = blockIdx.x * 256 + wv * 64;
    float (*stw)[68] = st[wv];

    half8 a[4][4];
    #pragma unroll
    for (int rt = 0; rt < 4; ++rt) {
        int r = row0 + rt * 16 + m;
        r = r < N ? r : N - 1;
        const _Float16* ap = A + (size_t)r * 128 + q * 8;
        #pragma unroll
        for (int ks = 0; ks < 4; ++ks) a[rt][ks] = *(const half8*)(ap + ks * 32);
    }

    #pragma unroll
    for (int cgi = 0; cgi < CGS; ++cgi) {
        int cgG = blockIdx.y * CGS + cgi;
        int col0 = cgG * 64;
        f32x4 acc[4][4];
        #pragma unroll
        for (int ct = 0; ct < 4; ++ct) {
            float bv = bias ? bias[col0 + ct * 16 + m] : 0.f;
            #pragma unroll
            for (int rt = 0; rt < 4; ++rt) acc[rt][ct] = (f32x4){bv, bv, bv, bv};
        }
        #pragma unroll
        for (int ks = 0; ks < 4; ++ks) {
            half8 b[4];
            #pragma unroll
            for (int ct = 0; ct < 4; ++ct)
                b[ct] = Bfrag[((size_t)cgG * 16 + ks * 4 + ct) * 64 + lane];
            #pragma unroll
            for (int rt = 0; rt < 4; ++rt)
                #pragma unroll
                for (int ct = 0; ct < 4; ++ct)
                    acc[rt][ct] = __builtin_amdgcn_mfma_f32_16x16x32_f16(a[rt][ks], b[ct], acc[rt][ct], 0, 0, 0);
        }
        // ---- LDS-staged wide-store epilogue, two 32-row half-passes ----
        #pragma unroll
        for (int hp = 0; hp < 2; ++hp) {
            #pragma unroll
            for (int rh = 0; rh < 2; ++rh) {
                int rt = hp * 2 + rh;
                #pragma unroll
                for (int reg = 0; reg < 4; ++reg) {
                    int lr = rh * 16 + q * 4 + reg;
                    #pragma unroll
                    for (int ct = 0; ct < 4; ++ct)
                        stw[lr][ct * 16 + m] = acc[rt][ct][reg];
                }
            }
            if constexpr (sizeof(OUT_T) == 2) {
                #pragma unroll
                for (int ps = 0; ps < 4; ++ps) {
                    int r = ps * 8 + (lane >> 3), c0 = (lane & 7) * 8;
                    float4 f0 = *(const float4*)&stw[r][c0];
                    float4 f1 = *(const float4*)&stw[r][c0 + 4];
                    if (RELU && (col0 + c0) < 256) {
                        f0.x = fmaxf(f0.x, 0.f); f0.y = fmaxf(f0.y, 0.f);
                        f0.z = fmaxf(f0.z, 0.f); f0.w = fmaxf(f0.w, 0.f);
                        f1.x = fmaxf(f1.x, 0.f); f1.y = fmaxf(f1.y, 0.f);
                        f1.z = fmaxf(f1.z, 0.f); f1.w = fmaxf(f1.w, 0.f);
                    }
                    half8 h;
                    h[0] = (_Float16)f0.x; h[1] = (_Float16)f0.y;
                    h[2] = (_Float16)f0.z; h[3] = (_Float16)f0.w;
                    h[4] = (_Float16)f1.x; h[5] = (_Float16)f1.y;
                    h[6] = (_Float16)f1.z; h[7] = (_Float16)f1.w;
                    int grow = row0 + hp * 32 + r;
                    if (grow < N)
                        *(half8*)((_Float16*)out + (size_t)grow * ldo + col0 + c0) = h;
                }
            } else {
                #pragma unroll
                for (int ps = 0; ps < 8; ++ps) {
                    int r = ps * 4 + (lane >> 4), c0 = (lane & 15) * 4;
                    float4 f = *(const float4*)&stw[r][c0];
                    int grow = row0 + hp * 32 + r;
                    if (grow < N)
                        *(float4*)((float*)out + (size_t)grow * ldo + col0 + c0) = f;
                }
            }
        }
    }
}

// ---- per-(window,head) kv & s reduction; wave per (w, 2h), no LDS/barriers ----
// k already relu'd by the GEMM epilogue.
__global__ __launch_bounds__(256) void k_kv_accum(const _Float16* __restrict__ qkv,
                                                  const int* __restrict__ offsets,
                                                  const int* __restrict__ counts,
                                                  float* __restrict__ kv_t,
                                                  float* __restrict__ s) {
    int w = blockIdx.x;
    int wv = threadIdx.x >> 6, lane = threadIdx.x & 63;
    int d = lane & 15, eq = lane >> 4;
    int off = offsets[w], cnt = counts[w];
    #pragma unroll
    for (int hh = 0; hh < 2; ++hh) {
        int h = wv * 2 + hh;
        float acc0 = 0.f, acc1 = 0.f, acc2 = 0.f, acc3 = 0.f, sacc = 0.f;
        const _Float16* base = qkv + (size_t)off * 384 + h * 16;
        int p = 0;
        for (; p + 4 <= cnt; p += 4) {
            _Float16 ka[4]; half4 va[4];
            #pragma unroll
            for (int u = 0; u < 4; ++u) {
                const _Float16* row = base + (size_t)(p + u) * 384;
                ka[u] = row[128 + d];
                va[u] = *(const half4*)(row + 256 + eq * 4);
            }
            #pragma unroll
            for (int u = 0; u < 4; ++u) {
                float kk = (float)ka[u];
                acc0 += kk * (float)va[u][0];
                acc1 += kk * (float)va[u][1];
                acc2 += kk * (float)va[u][2];
                acc3 += kk * (float)va[u][3];
                sacc += kk;
            }
        }
        for (; p < cnt; ++p) {
            const _Float16* row = base + (size_t)p * 384;
            float kk = (float)row[128 + d];
            half4 v4 = *(const half4*)(row + 256 + eq * 4);
            acc0 += kk * (float)v4[0];
            acc1 += kk * (float)v4[1];
            acc2 += kk * (float)v4[2];
            acc3 += kk * (float)v4[3];
            sacc += kk;
        }
        float* o = kv_t + (((size_t)(w * HH + h)) << 8);
        o[(eq * 4 + 0) * 16 + d] = acc0;
        o[(eq * 4 + 1) * 16 + d] = acc1;
        o[(eq * 4 + 2) * 16 + d] = acc2;
        o[(eq * 4 + 3) * 16 + d] = acc3;
        if (eq == 0) s[(((size_t)(w * HH + h)) << 4) + d] = sacc;
    }
}

// ---------------- linear attention with FUSED 3x3 pooling ----------------
// One wave per (window, head). The pooled kv/s operands are summed in fp32
// registers straight from kv_t/s (9 neighbors, L2-resident), converted to
// fp16 fragments — k_pool_all and the kvpt/sp round-trip are gone.
__global__ __launch_bounds__(256) void k_attn(const _Float16* __restrict__ qkv,
                                              const float* __restrict__ kv_t,
                                              const float* __restrict__ s,
                                              const int* __restrict__ offsets,
                                              const int* __restrict__ counts,
                                              _Float16* __restrict__ y_h) {
    int gid = blockIdx.x * 4 + (threadIdx.x >> 6);
    int w = gid >> 3, h = gid & 7;
    int lane = threadIdx.x & 63;
    int col = lane & 15;
    int kq = lane >> 4;
    int off = offsets[w], cnt = counts[w];
    bool klive = kq < 2;
    int koff = (kq & 1) * 8;

    int b = w >> 10, yy = (w >> 5) & 31, xx = w & 31;
    f32x4 k0 = {}, k1 = {}, s0 = {}, s1 = {};
    if (klive) {
        #pragma unroll
        for (int dy = -1; dy <= 1; ++dy)
            #pragma unroll
            for (int dx = -1; dx <= 1; ++dx) {
                int ny = yy + dy, nx = xx + dx;
                if (ny < 0 || ny >= 32 || nx < 0 || nx >= 32) continue;
                int nw = (b << 10) | (ny << 5) | nx;
                const float* kb = kv_t + (((size_t)(nw * HH + h)) << 8) + col * 16 + koff;
                k0 += *(const f32x4*)kb;
                k1 += *(const f32x4*)(kb + 4);
                const float* sb = s + (((size_t)(nw * HH + h)) << 4) + koff;
                s0 += *(const f32x4*)sb;
                s1 += *(const f32x4*)(sb + 4);
            }
    }
    half8 a_kv, a_s;
    #pragma unroll
    for (int i = 0; i < 4; ++i) {
        a_kv[i] = (_Float16)k0[i]; a_kv[4 + i] = (_Float16)k1[i];
        a_s[i]  = (_Float16)s0[i]; a_s[4 + i]  = (_Float16)s1[i];
    }

    #pragma unroll
    for (int c = 0; c < 3; ++c) {
        int p = c * 16 + col;
        int pc = p < cnt ? p : cnt - 1;
        // q already relu'd by the GEMM epilogue
        half8 b_q = *(const half8*)(qkv + (size_t)(off + pc) * 384 + h * 16 + koff);
        f32x4 acc = {};
        acc = __builtin_amdgcn_mfma_f32_16x16x32_f16(a_kv, b_q, acc, 0, 0, 0);
        f32x4 accs = {};
        accs = __builtin_amdgcn_mfma_f32_16x16x32_f16(a_s, b_q, accs, 0, 0, 0);
        float zinv = 1.f / (accs[0] + 1e-6f);
        half4 yo;
        #pragma unroll
        for (int i = 0; i < 4; ++i) yo[i] = (_Float16)(acc[i] * zinv);
        if (p < cnt)
            *(half4*)(y_h + (size_t)(off + p) * 128 + h * 16 + kq * 4) = yo;
    }
}

extern "C" void kernel_launch(void* const* d_in, const int* in_sizes, int n_in,
                              void* d_out, int out_size, void* d_ws, size_t ws_size,
                              hipStream_t stream) {
    const float* x     = (const float*)d_in[0];
    const float* Wqkv  = (const float*)d_in[1];
    const float* Wproj = (const float*)d_in[2];
    const float* bproj = (const float*)d_in[3];
    const int*   offsets = (const int*)d_in[4];
    const int*   counts  = (const int*)d_in[5];

    int N = in_sizes[0] / 128;

    char* ws = (char*)d_ws;
    float* kv_t = (float*)ws;                                    ws += (size_t)MWIN * HH * 256 * 4;
    float* s    = (float*)ws;                                    ws += (size_t)MWIN * HH * 16 * 4;
    _Float16* x_h    = (_Float16*)ws;                            ws += (size_t)N * 128 * 2;
    _Float16* qkv_h  = (_Float16*)ws;                            ws += (size_t)N * 384 * 2;
    _Float16* y_h    = (_Float16*)ws;                            ws += (size_t)N * 128 * 2;
    _Float16* fq     = (_Float16*)ws;                            ws += (size_t)6144 * 8 * 2;
    _Float16* fp     = (_Float16*)ws;                            ws += (size_t)2048 * 8 * 2;
    float* out  = (float*)d_out;

    int n8x = N * 128 / 8;
    k_cvt<<<(n8x + 255) / 256, 256, 0, stream>>>(x, x_h, n8x);
    k_prep_w<<<32, 256, 0, stream>>>(Wqkv, Wproj, fq, fp);

    int nrb = (N + 255) / 256;
    // QKV GEMM: 2 col-groups/block, grid.y=3, relu on q,k columns
    k_mfma_gemm<_Float16, 2, true><<<dim3(nrb, 3), 256, 0, stream>>>(
        x_h, (const half8*)fq, nullptr, qkv_h, 384, N);

    k_kv_accum<<<MWIN, 256, 0, stream>>>(qkv_h, offsets, counts, kv_t, s);

    k_attn<<<MWIN * 2, 256, 0, stream>>>(qkv_h, kv_t, s, offsets, counts, y_h);

    // Proj GEMM: 1 col-group/block, grid.y = 2
    k_mfma_gemm<float, 1, false><<<dim3(nrb, 2), 256, 0, stream>>>(
        y_h, (const half8*)fp, bproj, out, 128, N);
}

// Round 4
// 186.167 us; speedup vs baseline: 1.1962x; 1.0874x over previous
//
#include <hip/hip_runtime.h>

#define MWIN 2048
#define HH 8

typedef _Float16 half8 __attribute__((ext_vector_type(8)));
typedef _Float16 half4 __attribute__((ext_vector_type(4)));
typedef float f32x4 __attribute__((ext_vector_type(4)));

// ---- combined prep: weight fragmentization (blocks 0..31) + x fp32->fp16
// (blocks 32..). Weight frag layout: frag[cg][ks][ct][lane] (half8), so the
// GEMM b-load is ONE contiguous coalesced 1KB instruction.
__global__ __launch_bounds__(256) void k_prep(const float* __restrict__ x,
                                              _Float16* __restrict__ x_h, int n8,
                                              const float* __restrict__ Wqkv,
                                              const float* __restrict__ Wproj,
                                              _Float16* __restrict__ fq,
                                              _Float16* __restrict__ fp) {
    int bid = blockIdx.x;
    if (bid < 32) {
        int tid = bid * 256 + threadIdx.x;
        const float* src;
        _Float16* dst;
        if (tid < 6144) { src = Wqkv; dst = fq; }
        else {
            tid -= 6144;
            if (tid >= 2048) return;
            src = Wproj; dst = fp;
        }
        int lane = tid & 63, r = tid >> 6;
        int ct = r & 3, ks = (r >> 2) & 3, cg = r >> 4;
        int m = lane & 15, q = lane >> 4;
        const float* s_ = src + (size_t)(cg * 64 + ct * 16 + m) * 128 + q * 8 + ks * 32;
        float4 f0 = *(const float4*)s_;
        float4 f1 = *(const float4*)(s_ + 4);
        half8 h;
        h[0] = (_Float16)f0.x; h[1] = (_Float16)f0.y; h[2] = (_Float16)f0.z; h[3] = (_Float16)f0.w;
        h[4] = (_Float16)f1.x; h[5] = (_Float16)f1.y; h[6] = (_Float16)f1.z; h[7] = (_Float16)f1.w;
        *(half8*)(dst + (size_t)tid * 8) = h;
        return;
    }
    int i = (bid - 32) * 256 + threadIdx.x;
    if (i >= n8) return;
    float4 a = ((const float4*)x)[i * 2];
    float4 b = ((const float4*)x)[i * 2 + 1];
    half8 h;
    h[0] = (_Float16)a.x; h[1] = (_Float16)a.y; h[2] = (_Float16)a.z; h[3] = (_Float16)a.w;
    h[4] = (_Float16)b.x; h[5] = (_Float16)b.y; h[6] = (_Float16)b.z; h[7] = (_Float16)b.w;
    ((half8*)x_h)[i] = h;
}

// ---- MFMA GEMM, K=128. B pre-fragmentized; col groups split across blockIdx.y.
// LDS-staged wide-store epilogue; ReLU fused on cols<256 (q,k).
template <int CGS, bool RELU>
__global__ __launch_bounds__(256) void k_mfma_gemm(const _Float16* __restrict__ A,
                                                   const half8* __restrict__ Bfrag,
                                                   _Float16* __restrict__ out, int ldo,
                                                   int N) {
    __shared__ float st[4][32][68];
    int tid = threadIdx.x;
    int lane = tid & 63, wv = tid >> 6;
    int m = lane & 15, q = lane >> 4;
    int row0 = blockIdx.x * 256 + wv * 64;
    float (*stw)[68] = st[wv];

    half8 a[4][4];
    #pragma unroll
    for (int rt = 0; rt < 4; ++rt) {
        int r = row0 + rt * 16 + m;
        r = r < N ? r : N - 1;
        const _Float16* ap = A + (size_t)r * 128 + q * 8;
        #pragma unroll
        for (int ks = 0; ks < 4; ++ks) a[rt][ks] = *(const half8*)(ap + ks * 32);
    }

    #pragma unroll
    for (int cgi = 0; cgi < CGS; ++cgi) {
        int cgG = blockIdx.y * CGS + cgi;
        int col0 = cgG * 64;
        f32x4 acc[4][4];
        #pragma unroll
        for (int ct = 0; ct < 4; ++ct)
            #pragma unroll
            for (int rt = 0; rt < 4; ++rt) acc[rt][ct] = (f32x4){0.f, 0.f, 0.f, 0.f};
        #pragma unroll
        for (int ks = 0; ks < 4; ++ks) {
            half8 b[4];
            #pragma unroll
            for (int ct = 0; ct < 4; ++ct)
                b[ct] = Bfrag[((size_t)cgG * 16 + ks * 4 + ct) * 64 + lane];
            #pragma unroll
            for (int rt = 0; rt < 4; ++rt)
                #pragma unroll
                for (int ct = 0; ct < 4; ++ct)
                    acc[rt][ct] = __builtin_amdgcn_mfma_f32_16x16x32_f16(a[rt][ks], b[ct], acc[rt][ct], 0, 0, 0);
        }
        #pragma unroll
        for (int hp = 0; hp < 2; ++hp) {
            #pragma unroll
            for (int rh = 0; rh < 2; ++rh) {
                int rt = hp * 2 + rh;
                #pragma unroll
                for (int reg = 0; reg < 4; ++reg) {
                    int lr = rh * 16 + q * 4 + reg;
                    #pragma unroll
                    for (int ct = 0; ct < 4; ++ct)
                        stw[lr][ct * 16 + m] = acc[rt][ct][reg];
                }
            }
            #pragma unroll
            for (int ps = 0; ps < 4; ++ps) {
                int r = ps * 8 + (lane >> 3), c0 = (lane & 7) * 8;
                float4 f0 = *(const float4*)&stw[r][c0];
                float4 f1 = *(const float4*)&stw[r][c0 + 4];
                if (RELU && (col0 + c0) < 256) {
                    f0.x = fmaxf(f0.x, 0.f); f0.y = fmaxf(f0.y, 0.f);
                    f0.z = fmaxf(f0.z, 0.f); f0.w = fmaxf(f0.w, 0.f);
                    f1.x = fmaxf(f1.x, 0.f); f1.y = fmaxf(f1.y, 0.f);
                    f1.z = fmaxf(f1.z, 0.f); f1.w = fmaxf(f1.w, 0.f);
                }
                half8 h;
                h[0] = (_Float16)f0.x; h[1] = (_Float16)f0.y;
                h[2] = (_Float16)f0.z; h[3] = (_Float16)f0.w;
                h[4] = (_Float16)f1.x; h[5] = (_Float16)f1.y;
                h[6] = (_Float16)f1.z; h[7] = (_Float16)f1.w;
                int grow = row0 + hp * 32 + r;
                if (grow < N)
                    *(half8*)(out + (size_t)grow * ldo + col0 + c0) = h;
            }
        }
    }
}

// ---- per-(window,head) kv & s reduction; wave per (w, 2h) ----
__global__ __launch_bounds__(256) void k_kv_accum(const _Float16* __restrict__ qkv,
                                                  const int* __restrict__ offsets,
                                                  const int* __restrict__ counts,
                                                  float* __restrict__ kv_t,
                                                  float* __restrict__ s) {
    int w = blockIdx.x;
    int wv = threadIdx.x >> 6, lane = threadIdx.x & 63;
    int d = lane & 15, eq = lane >> 4;
    int off = offsets[w], cnt = counts[w];
    #pragma unroll
    for (int hh = 0; hh < 2; ++hh) {
        int h = wv * 2 + hh;
        float acc0 = 0.f, acc1 = 0.f, acc2 = 0.f, acc3 = 0.f, sacc = 0.f;
        const _Float16* base = qkv + (size_t)off * 384 + h * 16;
        int p = 0;
        for (; p + 4 <= cnt; p += 4) {
            _Float16 ka[4]; half4 va[4];
            #pragma unroll
            for (int u = 0; u < 4; ++u) {
                const _Float16* row = base + (size_t)(p + u) * 384;
                ka[u] = row[128 + d];
                va[u] = *(const half4*)(row + 256 + eq * 4);
            }
            #pragma unroll
            for (int u = 0; u < 4; ++u) {
                float kk = (float)ka[u];
                acc0 += kk * (float)va[u][0];
                acc1 += kk * (float)va[u][1];
                acc2 += kk * (float)va[u][2];
                acc3 += kk * (float)va[u][3];
                sacc += kk;
            }
        }
        for (; p < cnt; ++p) {
            const _Float16* row = base + (size_t)p * 384;
            float kk = (float)row[128 + d];
            half4 v4 = *(const half4*)(row + 256 + eq * 4);
            acc0 += kk * (float)v4[0];
            acc1 += kk * (float)v4[1];
            acc2 += kk * (float)v4[2];
            acc3 += kk * (float)v4[3];
            sacc += kk;
        }
        float* o = kv_t + (((size_t)(w * HH + h)) << 8);
        o[(eq * 4 + 0) * 16 + d] = acc0;
        o[(eq * 4 + 1) * 16 + d] = acc1;
        o[(eq * 4 + 2) * 16 + d] = acc2;
        o[(eq * 4 + 3) * 16 + d] = acc3;
        if (eq == 0) s[(((size_t)(w * HH + h)) << 4) + d] = sacc;
    }
}

// ---------------- fused attn + 3x3 pool + output projection ----------------
// One block (512 thr = 8 waves) per window. Wave h: pool kv/s from 9 neighbor
// windows (L2-resident), attention MFMA -> y-slice into LDS. Barrier. Then
// the 8 waves do the [48x128]x[128x128] proj GEMM from LDS with fragmentized
// Wproj, stage to LDS, and store rows<cnt as coalesced float4 + bias.
// Kills the y_h 40MB round-trip and one dispatch drain boundary.
__global__ __launch_bounds__(512) void k_attn_proj(const _Float16* __restrict__ qkv,
                                                   const float* __restrict__ kv_t,
                                                   const float* __restrict__ s,
                                                   const half8* __restrict__ fp,
                                                   const float* __restrict__ bproj,
                                                   const int* __restrict__ offsets,
                                                   const int* __restrict__ counts,
                                                   float* __restrict__ out) {
    __shared__ _Float16 y_t[48][136];   // padded: row stride 272B
    __shared__ float o_t[48][132];
    int w = blockIdx.x;
    int h = threadIdx.x >> 6;           // wave = head
    int lane = threadIdx.x & 63;
    int col = lane & 15;
    int kq = lane >> 4;
    int off = offsets[w], cnt = counts[w];
    bool klive = kq < 2;
    int koff = (kq & 1) * 8;

    // ---- 3x3 pooled kv,s in fp32 registers ----
    int b = w >> 10, yy = (w >> 5) & 31, xx = w & 31;
    f32x4 k0 = {}, k1 = {}, s0 = {}, s1 = {};
    if (klive) {
        #pragma unroll
        for (int dy = -1; dy <= 1; ++dy)
            #pragma unroll
            for (int dx = -1; dx <= 1; ++dx) {
                int ny = yy + dy, nx = xx + dx;
                if (ny < 0 || ny >= 32 || nx < 0 || nx >= 32) continue;
                int nw = (b << 10) | (ny << 5) | nx;
                const float* kb = kv_t + (((size_t)(nw * HH + h)) << 8) + col * 16 + koff;
                k0 += *(const f32x4*)kb;
                k1 += *(const f32x4*)(kb + 4);
                const float* sb = s + (((size_t)(nw * HH + h)) << 4) + koff;
                s0 += *(const f32x4*)sb;
                s1 += *(const f32x4*)(sb + 4);
            }
    }
    half8 a_kv, a_s;
    #pragma unroll
    for (int i = 0; i < 4; ++i) {
        a_kv[i] = (_Float16)k0[i]; a_kv[4 + i] = (_Float16)k1[i];
        a_s[i]  = (_Float16)s0[i]; a_s[4 + i]  = (_Float16)s1[i];
    }

    // ---- attention: y slice (this head's 16 dims for 48 points) -> LDS ----
    #pragma unroll
    for (int c = 0; c < 3; ++c) {
        int p = c * 16 + col;
        int pc = p < cnt ? p : cnt - 1;
        half8 b_q = *(const half8*)(qkv + (size_t)(off + pc) * 384 + h * 16 + koff);
        f32x4 acc = {};
        acc = __builtin_amdgcn_mfma_f32_16x16x32_f16(a_kv, b_q, acc, 0, 0, 0);
        f32x4 accs = {};
        accs = __builtin_amdgcn_mfma_f32_16x16x32_f16(a_s, b_q, accs, 0, 0, 0);
        float zinv = 1.f / (accs[0] + 1e-6f);
        half4 yo;
        #pragma unroll
        for (int i = 0; i < 4; ++i) yo[i] = (_Float16)(acc[i] * zinv);
        *(half4*)&y_t[p][h * 16 + kq * 4] = yo;
    }
    __syncthreads();

    // ---- projection: O[p][c] = sum_j y[p][j] * Wp[c][j] + bias[c] ----
    int m = col, q = kq;
    int ct = h;                         // wave owns output col-tile ct (16 cols)
    int cg = ct >> 2, ctl = ct & 3;
    half8 bfr[4];
    #pragma unroll
    for (int ks = 0; ks < 4; ++ks)
        bfr[ks] = fp[((size_t)cg * 16 + ks * 4 + ctl) * 64 + lane];
    float bv = bproj[ct * 16 + m];
    #pragma unroll
    for (int rt = 0; rt < 3; ++rt) {
        f32x4 acc = (f32x4){bv, bv, bv, bv};
        #pragma unroll
        for (int ks = 0; ks < 4; ++ks) {
            half8 af = *(const half8*)&y_t[rt * 16 + m][q * 8 + ks * 32];
            acc = __builtin_amdgcn_mfma_f32_16x16x32_f16(af, bfr[ks], acc, 0, 0, 0);
        }
        #pragma unroll
        for (int reg = 0; reg < 4; ++reg)
            o_t[rt * 16 + q * 4 + reg][ct * 16 + m] = acc[reg];
    }
    __syncthreads();

    // ---- coalesced float4 store of rows < cnt ----
    #pragma unroll
    for (int it = 0; it < 3; ++it) {
        int j = it * 512 + threadIdx.x;
        int r = j >> 5, c4 = j & 31;
        if (r < cnt)
            *(float4*)(out + ((size_t)(off + r) << 7) + c4 * 4) = *(const float4*)&o_t[r][c4 * 4];
    }
}

extern "C" void kernel_launch(void* const* d_in, const int* in_sizes, int n_in,
                              void* d_out, int out_size, void* d_ws, size_t ws_size,
                              hipStream_t stream) {
    const float* x     = (const float*)d_in[0];
    const float* Wqkv  = (const float*)d_in[1];
    const float* Wproj = (const float*)d_in[2];
    const float* bproj = (const float*)d_in[3];
    const int*   offsets = (const int*)d_in[4];
    const int*   counts  = (const int*)d_in[5];

    int N = in_sizes[0] / 128;

    char* ws = (char*)d_ws;
    float* kv_t = (float*)ws;                                    ws += (size_t)MWIN * HH * 256 * 4;
    float* s    = (float*)ws;                                    ws += (size_t)MWIN * HH * 16 * 4;
    _Float16* x_h    = (_Float16*)ws;                            ws += (size_t)N * 128 * 2;
    _Float16* qkv_h  = (_Float16*)ws;                            ws += (size_t)N * 384 * 2;
    _Float16* fq     = (_Float16*)ws;                            ws += (size_t)6144 * 8 * 2;
    _Float16* fp     = (_Float16*)ws;                            ws += (size_t)2048 * 8 * 2;
    float* out  = (float*)d_out;

    int n8x = N * 128 / 8;
    k_prep<<<32 + (n8x + 255) / 256, 256, 0, stream>>>(x, x_h, n8x, Wqkv, Wproj, fq, fp);

    int nrb = (N + 255) / 256;
    k_mfma_gemm<2, true><<<dim3(nrb, 3), 256, 0, stream>>>(
        x_h, (const half8*)fq, qkv_h, 384, N);

    k_kv_accum<<<MWIN, 256, 0, stream>>>(qkv_h, offsets, counts, kv_t, s);

    k_attn_proj<<<MWIN, 512, 0, stream>>>(qkv_h, kv_t, s, (const half8*)fp, bproj,
                                          offsets, counts, out);
}

// Round 5
// 178.535 us; speedup vs baseline: 1.2473x; 1.0427x over previous
//
#include <hip/hip_runtime.h>

#define MWIN 2048
#define HH 8

typedef _Float16 half8 __attribute__((ext_vector_type(8)));
typedef _Float16 half4 __attribute__((ext_vector_type(4)));
typedef float f32x4 __attribute__((ext_vector_type(4)));

// ---- combined prep: weight fragmentization (blocks 0..31) + x fp32->fp16
// into MFMA A-FRAGMENT order (blocks 32..).
// x_f layout: [tile=row/16][ks][lane]x(half8), lane=m+16q holds
// x[tile*16+m][q*8+ks*32 .. +7]. GEMM A-load becomes ONE contiguous coalesced
// 1KB instruction (was a 16-row x 256B-stride 16-line gather).
__global__ __launch_bounds__(256) void k_prep(const float* __restrict__ x,
                                              _Float16* __restrict__ x_f, int nxt,
                                              int N,
                                              const float* __restrict__ Wqkv,
                                              const float* __restrict__ Wproj,
                                              _Float16* __restrict__ fq,
                                              _Float16* __restrict__ fp) {
    int bid = blockIdx.x;
    if (bid < 32) {
        int tid = bid * 256 + threadIdx.x;
        const float* src;
        _Float16* dst;
        if (tid < 6144) { src = Wqkv; dst = fq; }
        else {
            tid -= 6144;
            if (tid >= 2048) return;
            src = Wproj; dst = fp;
        }
        int lane = tid & 63, r = tid >> 6;
        int ct = r & 3, ks = (r >> 2) & 3, cg = r >> 4;
        int m = lane & 15, q = lane >> 4;
        const float* s_ = src + (size_t)(cg * 64 + ct * 16 + m) * 128 + q * 8 + ks * 32;
        float4 f0 = *(const float4*)s_;
        float4 f1 = *(const float4*)(s_ + 4);
        half8 h;
        h[0] = (_Float16)f0.x; h[1] = (_Float16)f0.y; h[2] = (_Float16)f0.z; h[3] = (_Float16)f0.w;
        h[4] = (_Float16)f1.x; h[5] = (_Float16)f1.y; h[6] = (_Float16)f1.z; h[7] = (_Float16)f1.w;
        *(half8*)(dst + (size_t)tid * 8) = h;
        return;
    }
    int i = (bid - 32) * 256 + threadIdx.x;   // i = (t*4+ks)*64 + lane
    if (i >= nxt) return;
    int lane = i & 63, ks = (i >> 6) & 3, t = i >> 8;
    int m = lane & 15, q = lane >> 4;
    int row = t * 16 + m;
    row = row < N ? row : N - 1;
    const float* s_ = x + (size_t)row * 128 + q * 8 + ks * 32;
    float4 f0 = *(const float4*)s_;
    float4 f1 = *(const float4*)(s_ + 4);
    half8 h;
    h[0] = (_Float16)f0.x; h[1] = (_Float16)f0.y; h[2] = (_Float16)f0.z; h[3] = (_Float16)f0.w;
    h[4] = (_Float16)f1.x; h[5] = (_Float16)f1.y; h[6] = (_Float16)f1.z; h[7] = (_Float16)f1.w;
    *(half8*)(x_f + (size_t)i * 8) = h;
}

// ---- MFMA GEMM, K=128. A AND B pre-fragmentized (all hot-loop loads are
// contiguous coalesced 1KB wave-instructions). Col groups split across
// blockIdx.y. LDS-staged wide-store epilogue; ReLU fused on cols<256 (q,k).
template <int CGS, bool RELU>
__global__ __launch_bounds__(256) void k_mfma_gemm(const half8* __restrict__ Afrag,
                                                   const half8* __restrict__ Bfrag,
                                                   _Float16* __restrict__ out, int ldo,
                                                   int N) {
    __shared__ float st[4][32][68];
    int tid = threadIdx.x;
    int lane = tid & 63, wv = tid >> 6;
    int m = lane & 15, q = lane >> 4;
    int row0 = blockIdx.x * 256 + wv * 64;
    float (*stw)[68] = st[wv];

    half8 a[4][4];
    #pragma unroll
    for (int rt = 0; rt < 4; ++rt) {
        int t = (row0 >> 4) + rt;
        #pragma unroll
        for (int ks = 0; ks < 4; ++ks)
            a[rt][ks] = Afrag[((size_t)t * 4 + ks) * 64 + lane];
    }

    #pragma unroll
    for (int cgi = 0; cgi < CGS; ++cgi) {
        int cgG = blockIdx.y * CGS + cgi;
        int col0 = cgG * 64;
        f32x4 acc[4][4];
        #pragma unroll
        for (int ct = 0; ct < 4; ++ct)
            #pragma unroll
            for (int rt = 0; rt < 4; ++rt) acc[rt][ct] = (f32x4){0.f, 0.f, 0.f, 0.f};
        #pragma unroll
        for (int ks = 0; ks < 4; ++ks) {
            half8 b[4];
            #pragma unroll
            for (int ct = 0; ct < 4; ++ct)
                b[ct] = Bfrag[((size_t)cgG * 16 + ks * 4 + ct) * 64 + lane];
            #pragma unroll
            for (int rt = 0; rt < 4; ++rt)
                #pragma unroll
                for (int ct = 0; ct < 4; ++ct)
                    acc[rt][ct] = __builtin_amdgcn_mfma_f32_16x16x32_f16(a[rt][ks], b[ct], acc[rt][ct], 0, 0, 0);
        }
        #pragma unroll
        for (int hp = 0; hp < 2; ++hp) {
            #pragma unroll
            for (int rh = 0; rh < 2; ++rh) {
                int rt = hp * 2 + rh;
                #pragma unroll
                for (int reg = 0; reg < 4; ++reg) {
                    int lr = rh * 16 + q * 4 + reg;
                    #pragma unroll
                    for (int ct = 0; ct < 4; ++ct)
                        stw[lr][ct * 16 + m] = acc[rt][ct][reg];
                }
            }
            #pragma unroll
            for (int ps = 0; ps < 4; ++ps) {
                int r = ps * 8 + (lane >> 3), c0 = (lane & 7) * 8;
                float4 f0 = *(const float4*)&stw[r][c0];
                float4 f1 = *(const float4*)&stw[r][c0 + 4];
                if (RELU && (col0 + c0) < 256) {
                    f0.x = fmaxf(f0.x, 0.f); f0.y = fmaxf(f0.y, 0.f);
                    f0.z = fmaxf(f0.z, 0.f); f0.w = fmaxf(f0.w, 0.f);
                    f1.x = fmaxf(f1.x, 0.f); f1.y = fmaxf(f1.y, 0.f);
                    f1.z = fmaxf(f1.z, 0.f); f1.w = fmaxf(f1.w, 0.f);
                }
                half8 h;
                h[0] = (_Float16)f0.x; h[1] = (_Float16)f0.y;
                h[2] = (_Float16)f0.z; h[3] = (_Float16)f0.w;
                h[4] = (_Float16)f1.x; h[5] = (_Float16)f1.y;
                h[6] = (_Float16)f1.z; h[7] = (_Float16)f1.w;
                int grow = row0 + hp * 32 + r;
                if (grow < N)
                    *(half8*)(out + (size_t)grow * ldo + col0 + c0) = h;
            }
        }
    }
}

// ---- per-window kv & s reduction. 512 thr/block = 8 waves = one head each.
// k|v (cols 128..383 = contiguous 512B/row) staged into LDS with coalesced
// half8 loads (was: per-lane 2B/8B gathers at 768B row stride, 16 lines/load,
// serial over cnt x 2 heads). Compute reads are LDS broadcasts (conflict-free).
__global__ __launch_bounds__(512) void k_kv_accum(const _Float16* __restrict__ qkv,
                                                  const int* __restrict__ offsets,
                                                  const int* __restrict__ counts,
                                                  float* __restrict__ kv_t,
                                                  float* __restrict__ s) {
    __shared__ _Float16 kvl[40][256];
    int w = blockIdx.x;
    int off = offsets[w], cnt = counts[w];
    int tid = threadIdx.x;
    for (int base = 0; base < cnt; base += 16) {
        int p = base + (tid >> 5);
        if (p < cnt)
            *(half8*)&kvl[p][(tid & 31) * 8] =
                *(const half8*)(qkv + (size_t)(off + p) * 384 + 128 + (tid & 31) * 8);
    }
    __syncthreads();
    int h = tid >> 6, lane = tid & 63;
    int d = lane & 15, eq = lane >> 4;
    float a0 = 0.f, a1 = 0.f, a2 = 0.f, a3 = 0.f, sa = 0.f;
    for (int p = 0; p < cnt; ++p) {
        float kk = (float)kvl[p][h * 16 + d];
        half4 v4 = *(const half4*)&kvl[p][128 + h * 16 + eq * 4];
        a0 += kk * (float)v4[0];
        a1 += kk * (float)v4[1];
        a2 += kk * (float)v4[2];
        a3 += kk * (float)v4[3];
        sa += kk;
    }
    float* o = kv_t + (((size_t)(w * HH + h)) << 8);
    o[(eq * 4 + 0) * 16 + d] = a0;
    o[(eq * 4 + 1) * 16 + d] = a1;
    o[(eq * 4 + 2) * 16 + d] = a2;
    o[(eq * 4 + 3) * 16 + d] = a3;
    if (eq == 0) s[(((size_t)(w * HH + h)) << 4) + d] = sa;
}

// ---------------- fused attn + 3x3 pool + output projection ----------------
// One block (512 thr = 8 waves) per window. Wave h: pool kv/s from 9 neighbor
// windows (L2-resident), attention MFMA -> y-slice into LDS. Barrier. Then
// the 8 waves do the [48x128]x[128x128] proj GEMM from LDS with fragmentized
// Wproj, stage to LDS, and store rows<cnt as coalesced float4 + bias.
__global__ __launch_bounds__(512) void k_attn_proj(const _Float16* __restrict__ qkv,
                                                   const float* __restrict__ kv_t,
                                                   const float* __restrict__ s,
                                                   const half8* __restrict__ fp,
                                                   const float* __restrict__ bproj,
                                                   const int* __restrict__ offsets,
                                                   const int* __restrict__ counts,
                                                   float* __restrict__ out) {
    __shared__ _Float16 y_t[48][136];
    __shared__ float o_t[48][132];
    int w = blockIdx.x;
    int h = threadIdx.x >> 6;
    int lane = threadIdx.x & 63;
    int col = lane & 15;
    int kq = lane >> 4;
    int off = offsets[w], cnt = counts[w];
    bool klive = kq < 2;
    int koff = (kq & 1) * 8;

    int b = w >> 10, yy = (w >> 5) & 31, xx = w & 31;
    f32x4 k0 = {}, k1 = {}, s0 = {}, s1 = {};
    if (klive) {
        #pragma unroll
        for (int dy = -1; dy <= 1; ++dy)
            #pragma unroll
            for (int dx = -1; dx <= 1; ++dx) {
                int ny = yy + dy, nx = xx + dx;
                if (ny < 0 || ny >= 32 || nx < 0 || nx >= 32) continue;
                int nw = (b << 10) | (ny << 5) | nx;
                const float* kb = kv_t + (((size_t)(nw * HH + h)) << 8) + col * 16 + koff;
                k0 += *(const f32x4*)kb;
                k1 += *(const f32x4*)(kb + 4);
                const float* sb = s + (((size_t)(nw * HH + h)) << 4) + koff;
                s0 += *(const f32x4*)sb;
                s1 += *(const f32x4*)(sb + 4);
            }
    }
    half8 a_kv, a_s;
    #pragma unroll
    for (int i = 0; i < 4; ++i) {
        a_kv[i] = (_Float16)k0[i]; a_kv[4 + i] = (_Float16)k1[i];
        a_s[i]  = (_Float16)s0[i]; a_s[4 + i]  = (_Float16)s1[i];
    }

    #pragma unroll
    for (int c = 0; c < 3; ++c) {
        int p = c * 16 + col;
        int pc = p < cnt ? p : cnt - 1;
        half8 b_q = *(const half8*)(qkv + (size_t)(off + pc) * 384 + h * 16 + koff);
        f32x4 acc = {};
        acc = __builtin_amdgcn_mfma_f32_16x16x32_f16(a_kv, b_q, acc, 0, 0, 0);
        f32x4 accs = {};
        accs = __builtin_amdgcn_mfma_f32_16x16x32_f16(a_s, b_q, accs, 0, 0, 0);
        float zinv = 1.f / (accs[0] + 1e-6f);
        half4 yo;
        #pragma unroll
        for (int i = 0; i < 4; ++i) yo[i] = (_Float16)(acc[i] * zinv);
        *(half4*)&y_t[p][h * 16 + kq * 4] = yo;
    }
    __syncthreads();

    int m = col, q = kq;
    int ct = h;
    int cg = ct >> 2, ctl = ct & 3;
    half8 bfr[4];
    #pragma unroll
    for (int ks = 0; ks < 4; ++ks)
        bfr[ks] = fp[((size_t)cg * 16 + ks * 4 + ctl) * 64 + lane];
    float bv = bproj[ct * 16 + m];
    #pragma unroll
    for (int rt = 0; rt < 3; ++rt) {
        f32x4 acc = (f32x4){bv, bv, bv, bv};
        #pragma unroll
        for (int ks = 0; ks < 4; ++ks) {
            half8 af = *(const half8*)&y_t[rt * 16 + m][q * 8 + ks * 32];
            acc = __builtin_amdgcn_mfma_f32_16x16x32_f16(af, bfr[ks], acc, 0, 0, 0);
        }
        #pragma unroll
        for (int reg = 0; reg < 4; ++reg)
            o_t[rt * 16 + q * 4 + reg][ct * 16 + m] = acc[reg];
    }
    __syncthreads();

    #pragma unroll
    for (int it = 0; it < 3; ++it) {
        int j = it * 512 + threadIdx.x;
        int r = j >> 5, c4 = j & 31;
        if (r < cnt)
            *(float4*)(out + ((size_t)(off + r) << 7) + c4 * 4) = *(const float4*)&o_t[r][c4 * 4];
    }
}

extern "C" void kernel_launch(void* const* d_in, const int* in_sizes, int n_in,
                              void* d_out, int out_size, void* d_ws, size_t ws_size,
                              hipStream_t stream) {
    const float* x     = (const float*)d_in[0];
    const float* Wqkv  = (const float*)d_in[1];
    const float* Wproj = (const float*)d_in[2];
    const float* bproj = (const float*)d_in[3];
    const int*   offsets = (const int*)d_in[4];
    const int*   counts  = (const int*)d_in[5];

    int N = in_sizes[0] / 128;
    int nrb = (N + 255) / 256;
    int Npad = nrb * 256;

    char* ws = (char*)d_ws;
    float* kv_t = (float*)ws;                                    ws += (size_t)MWIN * HH * 256 * 4;
    float* s    = (float*)ws;                                    ws += (size_t)MWIN * HH * 16 * 4;
    _Float16* x_f    = (_Float16*)ws;                            ws += (size_t)Npad * 128 * 2;
    _Float16* qkv_h  = (_Float16*)ws;                            ws += (size_t)N * 384 * 2;
    _Float16* fq     = (_Float16*)ws;                            ws += (size_t)6144 * 8 * 2;
    _Float16* fp     = (_Float16*)ws;                            ws += (size_t)2048 * 8 * 2;
    float* out  = (float*)d_out;

    int nxt = Npad * 16;   // x_f half8 count
    k_prep<<<32 + (nxt + 255) / 256, 256, 0, stream>>>(x, x_f, nxt, N, Wqkv, Wproj, fq, fp);

    k_mfma_gemm<2, true><<<dim3(nrb, 3), 256, 0, stream>>>(
        (const half8*)x_f, (const half8*)fq, qkv_h, 384, N);

    k_kv_accum<<<MWIN, 512, 0, stream>>>(qkv_h, offsets, counts, kv_t, s);

    k_attn_proj<<<MWIN, 512, 0, stream>>>(qkv_h, kv_t, s, (const half8*)fp, bproj,
                                          offsets, counts, out);
}